// Round 2
// baseline (1312.747 us; speedup 1.0000x reference)
//
#include <hip/hip_runtime.h>
#include <math.h>

#define BB   32
#define DD   128
#define HH   64
#define WW   64
#define KK   1024
#define HWW  (HH * WW)      // 4096
#define NPIX (BB * HWW)     // 131072
#define EPS  1e-4f          // > 3x worst-case |screen - exact| comparison bound

// ws layout (floats): wT[131072] | e2[1024] | ctr(int, at +132096) pad to 132160 | list[131072]
#define WS_WT    0
#define WS_E2    131072
#define WS_CTR   132096
#define WS_LIST  132160

// ---------------------------------------------------------------------------
// Prep: transpose weight [D][K] -> wT [K][D], e2[k] = sum_d w^2 in numpy order
// (sequential d, separate mul/add rounding). Also zeroes the hard counter.
// ---------------------------------------------------------------------------
__global__ void prep_kernel(const float* __restrict__ w,
                            float* __restrict__ wT,
                            float* __restrict__ e2,
                            int* __restrict__ hard_ctr) {
    int k = blockIdx.x * blockDim.x + threadIdx.x;
    if (k == 0) hard_ctr[0] = 0;
    if (k >= KK) return;
    float acc = 0.0f;
    for (int d = 0; d < DD; ++d) {
        float v = w[d * KK + k];
        wT[k * DD + d] = v;
        acc = __fadd_rn(acc, __fmul_rn(v, v));
    }
    e2[k] = acc;
}

// ---------------------------------------------------------------------------
// Screening: one thread = one pixel, x in VGPRs, codebook via wave-uniform
// loads (scalar path, no LDS, no barriers). Ranks by s(k) = e2[k] - 2*x.e(k)
// with FMA + 4-way reassociation (bounded deviation from the exact d2
// ordering). Pixels whose top-2 gap <= EPS are appended to the hard list.
// ---------------------------------------------------------------------------
__global__ __launch_bounds__(256) void vq_screen(
        const float* __restrict__ x,
        const float* __restrict__ wT,
        const float* __restrict__ e2,
        float* __restrict__ out,
        int* __restrict__ hard_list,
        int* __restrict__ hard_ctr) {
    const int tid = threadIdx.x;
    const int p   = blockIdx.x * 256 + tid;
    const int b   = p >> 12;
    const int hw  = p & (HWW - 1);

    const float* xp = x + (size_t)b * DD * HWW + hw;
    float xv[DD];
#pragma unroll
    for (int d = 0; d < DD; ++d) xv[d] = xp[(size_t)d * HWW];

    float best1 = INFINITY, best2 = INFINITY;
    int   k1    = 0;

    for (int k = 0; k < KK; ++k) {
        const float* wk = wT + k * DD;   // wave-uniform address -> s_load
        float a0 = 0.0f, a1 = 0.0f, a2 = 0.0f, a3 = 0.0f;
#pragma unroll
        for (int d = 0; d < DD; d += 4) {
            a0 += xv[d + 0] * wk[d + 0];   // FMA-contracted, 4 indep chains
            a1 += xv[d + 1] * wk[d + 1];
            a2 += xv[d + 2] * wk[d + 2];
            a3 += xv[d + 3] * wk[d + 3];
        }
        float s = e2[k] - 2.0f * ((a0 + a1) + (a2 + a3));
        bool lt1 = s < best1;
        best2 = lt1 ? best1 : (s < best2 ? s : best2);
        best1 = lt1 ? s : best1;
        k1    = lt1 ? k : k1;
    }

    // argmin output (overwritten later for hard pixels)
    out[(size_t)DD * NPIX + p] = (float)k1;

    // gather winning codeword -> [b, d, h, w]
    const float4* wbest = (const float4*)(wT + (size_t)k1 * DD);
    float* op = out + (size_t)b * DD * HWW + hw;
#pragma unroll
    for (int d4 = 0; d4 < DD / 4; ++d4) {
        float4 wv = wbest[d4];
        op[(size_t)(4 * d4 + 0) * HWW] = wv.x;
        op[(size_t)(4 * d4 + 1) * HWW] = wv.y;
        op[(size_t)(4 * d4 + 2) * HWW] = wv.z;
        op[(size_t)(4 * d4 + 3) * HWW] = wv.w;
    }

    if (best2 - best1 <= EPS) {
        int idx = atomicAdd(hard_ctr, 1);
        hard_list[idx] = p;
    }
}

// ---------------------------------------------------------------------------
// Exact fallback: 1024 waves stride over the hard list; one wave per pixel.
// Lane owns 16 contiguous codebook rows; per-row accumulation is the byte-
// exact round-1 arithmetic (sequential d, __fadd_rn(__fmul_rn), x2 included,
// d2 = (x2 - 2*xe) + e2 with each step rounded). Tie rule: min d2, then min k
// (== numpy first occurrence). Overwrites argmin + gathered row.
// ---------------------------------------------------------------------------
__global__ __launch_bounds__(256) void vq_fallback(
        const float* __restrict__ x,
        const float* __restrict__ wT,
        const float* __restrict__ e2,
        float* __restrict__ out,
        const int* __restrict__ hard_list,
        const int* __restrict__ hard_ctr) {
    const int wave = (blockIdx.x * 256 + threadIdx.x) >> 6;   // 0..1023
    const int lane = threadIdx.x & 63;
    const int count = hard_ctr[0];

    for (int j = wave; j < count; j += 1024) {
        const int p  = hard_list[j];
        const int b  = p >> 12;
        const int hw = p & (HWW - 1);

        const float* xp = x + (size_t)b * DD * HWW + hw;
        float xv[DD];
#pragma unroll
        for (int d = 0; d < DD; ++d) xv[d] = xp[(size_t)d * HWW];  // broadcast

        float x2 = 0.0f;
#pragma unroll
        for (int d = 0; d < DD; ++d) x2 = __fadd_rn(x2, __fmul_rn(xv[d], xv[d]));

        float bestd = INFINITY;
        int   bestk = 0;
        for (int kk = 0; kk < 16; ++kk) {
            const int k = lane * 16 + kk;               // lane-partitioned, ascending
            const float* wk = wT + (size_t)k * DD;
            float a = 0.0f;
            for (int d = 0; d < DD; ++d)
                a = __fadd_rn(a, __fmul_rn(xv[d], wk[d]));
            float d2 = __fadd_rn(__fsub_rn(x2, 2.0f * a), e2[k]);
            if (d2 < bestd) { bestd = d2; bestk = k; }
        }
        // xor-butterfly reduce: min d2, tie -> min k (all lanes converge)
#pragma unroll
        for (int off = 32; off; off >>= 1) {
            float od = __shfl_xor(bestd, off);
            int   ok = __shfl_xor(bestk, off);
            if (od < bestd || (od == bestd && ok < bestk)) { bestd = od; bestk = ok; }
        }

        if (lane == 0) out[(size_t)DD * NPIX + p] = (float)bestk;
        const float* wb = wT + (size_t)bestk * DD;
        float* op = out + (size_t)b * DD * HWW + hw;
        op[(size_t)lane * HWW]        = wb[lane];
        op[(size_t)(lane + 64) * HWW] = wb[lane + 64];
    }
}

extern "C" void kernel_launch(void* const* d_in, const int* in_sizes, int n_in,
                              void* d_out, int out_size, void* d_ws, size_t ws_size,
                              hipStream_t stream) {
    const float* x = (const float*)d_in[0];   // [32,128,64,64]
    const float* w = (const float*)d_in[1];   // [128,1024]
    float* out = (float*)d_out;
    float* wsf = (float*)d_ws;

    float* wT       = wsf + WS_WT;
    float* e2       = wsf + WS_E2;
    int*   hard_ctr = (int*)(wsf + WS_CTR);
    int*   hard_list= (int*)(wsf + WS_LIST);

    prep_kernel<<<dim3(KK / 256), dim3(256), 0, stream>>>(w, wT, e2, hard_ctr);
    vq_screen<<<dim3(NPIX / 256), dim3(256), 0, stream>>>(x, wT, e2, out,
                                                          hard_list, hard_ctr);
    vq_fallback<<<dim3(256), dim3(256), 0, stream>>>(x, wT, e2, out,
                                                     hard_list, hard_ctr);
}

// Round 3
// 477.153 us; speedup vs baseline: 2.7512x; 2.7512x over previous
//
#include <hip/hip_runtime.h>
#include <math.h>

#define BB   32
#define DD   128
#define HH   64
#define WW   64
#define KK   1024
#define HWW  (HH * WW)      // 4096
#define NPIX (BB * HWW)     // 131072
#define EPS  1e-4f          // covers exact-formula ulp(~128) wobble (<=6.1e-5)
                            // + split-bf16 screen error (<1e-5) + margin

// ws layout in floats:
#define WS_WT    0           // fp32 wT[K][D]           131072
#define WS_E2    131072      // fp32 e2[K]                1024
#define WS_CTR   132096      // int counter (pad 64)
#define WS_LIST  132160      // int hard_list[NPIX]     131072
#define WS_BHI   263232      // bf16 B-frags hi (131072 shorts = 65536 float slots)
#define WS_BLO   328768      // bf16 B-frags lo
// total 394304 floats = 1.54 MB

typedef short  short8  __attribute__((ext_vector_type(8)));
typedef float  floatx4 __attribute__((ext_vector_type(4)));

// Manual RNE float->bf16 (no NaN inputs here); deterministic, header-proof.
static __device__ __forceinline__ unsigned short f2bf(float x) {
    unsigned u = __float_as_uint(x);
    unsigned r = (u + 0x7fffu + ((u >> 16) & 1u)) >> 16;
    return (unsigned short)r;
}
static __device__ __forceinline__ float bf2f(unsigned short b) {
    return __uint_as_float(((unsigned)b) << 16);
}

// ---------------------------------------------------------------------------
// Prep 1: transpose w[D][K] -> wT[K][D] fp32. 32768 threads, coalesced reads.
// ---------------------------------------------------------------------------
__global__ void prep_wt(const float* __restrict__ w, float* __restrict__ wT) {
    int t  = blockIdx.x * 256 + threadIdx.x;   // 0..32767
    int k  = t & 1023;
    int d4 = t >> 10;                           // 0..31
    float4 v;
    v.x = w[(d4 * 4 + 0) * KK + k];
    v.y = w[(d4 * 4 + 1) * KK + k];
    v.z = w[(d4 * 4 + 2) * KK + k];
    v.w = w[(d4 * 4 + 3) * KK + k];
    *(float4*)(wT + (size_t)k * DD + d4 * 4) = v;
}

// ---------------------------------------------------------------------------
// Prep 2: pack bf16 hi/lo B-fragments in MFMA B-operand layout.
// Fragment unit u = (ktile*4 + chunk)*64 + lane holds 8 halves:
//   B[kdim = chunk*32 + (lane>>4)*8 + j][n = ktile*16 + (lane&15)], j=0..7
// ---------------------------------------------------------------------------
__global__ void prep_bfrag(const float* __restrict__ w,
                           short8* __restrict__ bhi, short8* __restrict__ blo) {
    int t     = blockIdx.x * 256 + threadIdx.x;  // 0..16383
    int lane  = t & 63;
    int chunk = (t >> 6) & 3;
    int ktile = t >> 8;
    int kcol  = ktile * 16 + (lane & 15);
    int d0    = chunk * 32 + (lane >> 4) * 8;
    short8 h, l;
#pragma unroll
    for (int j = 0; j < 8; ++j) {
        float wv = w[(size_t)(d0 + j) * KK + kcol];
        unsigned short hb = f2bf(wv);
        h[j] = (short)hb;
        l[j] = (short)f2bf(wv - bf2f(hb));
    }
    bhi[t] = h;
    blo[t] = l;
}

// ---------------------------------------------------------------------------
// Prep 3: e2[k] in numpy order (sequential d, separate mul/add); zero counter.
// ---------------------------------------------------------------------------
__global__ void prep_e2(const float* __restrict__ wT, float* __restrict__ e2,
                        int* __restrict__ ctr) {
    int k = blockIdx.x * 256 + threadIdx.x;
    if (k == 0) ctr[0] = 0;
    if (k >= KK) return;
    const float* row = wT + (size_t)k * DD;
    float acc = 0.0f;
    for (int d = 0; d < DD; ++d) acc = __fadd_rn(acc, __fmul_rn(row[d], row[d]));
    e2[k] = acc;
}

// ---------------------------------------------------------------------------
// Screen: block = 4 waves, wave = 16 pixels x all 1024 k via bf16 MFMA.
// s(k) = e2[k] - 2*dot(x,w_k), dot = xh*wh + xh*wl + xl*wh (split bf16,
// fp32 accum). Per-lane online top-2 over its k-column, then 16-lane
// butterfly merge. Gap <= EPS -> hard list for the exact fallback.
// ---------------------------------------------------------------------------
__global__ __launch_bounds__(256) void vq_screen(
        const float* __restrict__ x,
        const float* __restrict__ wT,
        const float* __restrict__ e2,
        const short8* __restrict__ bhi,
        const short8* __restrict__ blo,
        float* __restrict__ out,
        int* __restrict__ hard_list,
        int* __restrict__ hard_ctr) {
    __shared__ int sk1[4][16];

    const int tid  = threadIdx.x;
    const int wave = tid >> 6;
    const int lane = tid & 63;
    const int q    = lane >> 4;       // quad
    const int col  = lane & 15;

    const int b        = blockIdx.x >> 6;                 // image
    const int wbase_hw = (blockIdx.x & 63) * 64 + wave * 16;
    const int hw       = wbase_hw + col;                  // this lane's pixel (as A-row m=col)

    // A fragments: x[pixel=col][d = chunk*32 + q*8 + j], bf16 hi/lo split
    short8 ahi[4], alo[4];
#pragma unroll
    for (int chunk = 0; chunk < 4; ++chunk) {
#pragma unroll
        for (int j = 0; j < 8; ++j) {
            int d = chunk * 32 + q * 8 + j;
            float xf = x[(size_t)(b * DD + d) * HWW + hw];
            unsigned short hb = f2bf(xf);
            ahi[chunk][j] = (short)hb;
            alo[chunk][j] = (short)f2bf(xf - bf2f(hb));
        }
    }

    float b1[4] = {INFINITY, INFINITY, INFINITY, INFINITY};
    float b2[4] = {INFINITY, INFINITY, INFINITY, INFINITY};
    int   k1[4] = {0, 0, 0, 0};

    for (int kt = 0; kt < KK / 16; ++kt) {
        const int ubase = kt * 4 * 64 + lane;
        short8 bh0 = bhi[ubase + 0 * 64], bh1 = bhi[ubase + 1 * 64];
        short8 bh2 = bhi[ubase + 2 * 64], bh3 = bhi[ubase + 3 * 64];
        short8 bl0 = blo[ubase + 0 * 64], bl1 = blo[ubase + 1 * 64];
        short8 bl2 = blo[ubase + 2 * 64], bl3 = blo[ubase + 3 * 64];
        float e2v = e2[kt * 16 + col];

        floatx4 accA = {0.f, 0.f, 0.f, 0.f};
        floatx4 accB = {0.f, 0.f, 0.f, 0.f};
        // pass hi*hi
        accA = __builtin_amdgcn_mfma_f32_16x16x32_bf16(ahi[0], bh0, accA, 0, 0, 0);
        accB = __builtin_amdgcn_mfma_f32_16x16x32_bf16(ahi[1], bh1, accB, 0, 0, 0);
        accA = __builtin_amdgcn_mfma_f32_16x16x32_bf16(ahi[2], bh2, accA, 0, 0, 0);
        accB = __builtin_amdgcn_mfma_f32_16x16x32_bf16(ahi[3], bh3, accB, 0, 0, 0);
        // pass hi*lo
        accA = __builtin_amdgcn_mfma_f32_16x16x32_bf16(ahi[0], bl0, accA, 0, 0, 0);
        accB = __builtin_amdgcn_mfma_f32_16x16x32_bf16(ahi[1], bl1, accB, 0, 0, 0);
        accA = __builtin_amdgcn_mfma_f32_16x16x32_bf16(ahi[2], bl2, accA, 0, 0, 0);
        accB = __builtin_amdgcn_mfma_f32_16x16x32_bf16(ahi[3], bl3, accB, 0, 0, 0);
        // pass lo*hi
        accA = __builtin_amdgcn_mfma_f32_16x16x32_bf16(alo[0], bh0, accA, 0, 0, 0);
        accB = __builtin_amdgcn_mfma_f32_16x16x32_bf16(alo[1], bh1, accB, 0, 0, 0);
        accA = __builtin_amdgcn_mfma_f32_16x16x32_bf16(alo[2], bh2, accA, 0, 0, 0);
        accB = __builtin_amdgcn_mfma_f32_16x16x32_bf16(alo[3], bh3, accB, 0, 0, 0);

        const int kcur = kt * 16 + col;
#pragma unroll
        for (int r = 0; r < 4; ++r) {
            float s = fmaf(-2.0f, accA[r] + accB[r], e2v);
            bool lt = s < b1[r];
            // b2' = median(s, b1, b2) = 2nd smallest of the union
            float mn = fminf(s, b1[r]), mx = fmaxf(s, b1[r]);
            b2[r] = fminf(mx, fminf(fmaxf(mn, b2[r]), fmaxf(b2[r], mn)));  // med3
            b2[r] = fminf(fmaxf(s, b1[r]), b2[r]) > 0 ? fminf(fmaxf(s, b1[r]), b2[r]) : fminf(fmaxf(s, b1[r]), b2[r]); // keep simple below
            b2[r] = fminf(fmaxf(s, b1[r]), b2[r]);   // correct med3: min(max(s,b1), b2) when b2 >= one of them
            k1[r] = lt ? kcur : k1[r];
            b1[r] = mn;
        }
    }

    // NOTE on b2 update above: b2' = min(max(s,b1_old), b2_old) is the exact
    // 2nd-smallest recurrence: if s<b1 -> max=b1_old (new 2nd) ; if b1<=s<b2
    // -> max=s ; else b2 stays. The med3 lines collapse to this final one.

    // Butterfly merge across the 16 lanes of this quad-group (cols 0..15).
#pragma unroll
    for (int off = 1; off < 16; off <<= 1) {
#pragma unroll
        for (int r = 0; r < 4; ++r) {
            float ob1 = __shfl_xor(b1[r], off);
            float ob2 = __shfl_xor(b2[r], off);
            int   ok1 = __shfl_xor(k1[r], off);
            float nb2 = fminf(fmaxf(b1[r], ob1), fminf(b2[r], ob2));
            bool take = (ob1 < b1[r]) || (ob1 == b1[r] && ok1 < k1[r]);
            b1[r] = take ? ob1 : b1[r];
            k1[r] = take ? ok1 : k1[r];
            b2[r] = nb2;
        }
    }

    // Lane G*16+r publishes pixel G*4+r (its reg r).
#pragma unroll
    for (int r = 0; r < 4; ++r) {
        if (col == r) {
            int plocal = q * 4 + r;                // pixel index within wave
            int P      = b * HWW * 0 + 0;          // (unused; compute below)
            int hwp    = wbase_hw + plocal;
            int Pg     = b * HWW + hwp;            // global pixel id
            out[(size_t)DD * NPIX + Pg] = (float)k1[r];
            sk1[wave][plocal] = k1[r];
            if (b2[r] - b1[r] <= EPS) {
                int idx = atomicAdd(hard_ctr, 1);
                hard_list[idx] = Pg;
            }
        }
    }
    __syncthreads();

    // Gather: lane = dgrp*16 + plocal ; d = i*4 + dgrp keeps 64B store runs.
    {
        const int plocal = lane & 15;
        const int dgrp   = lane >> 4;
        const int kk     = sk1[wave][plocal];
        const int hwp    = wbase_hw + plocal;
        const float* wrow = wT + (size_t)kk * DD;
#pragma unroll
        for (int i = 0; i < 32; ++i) {
            int d = i * 4 + dgrp;
            out[(size_t)(b * DD + d) * HWW + hwp] = wrow[d];
        }
    }
}

// ---------------------------------------------------------------------------
// Exact fallback: one block (256 thr) per hard pixel, 4 codewords per thread.
// Byte-exact round-1 arithmetic; lexicographic (d2,k) min via u64 pack
// (d2 > 0 always here, so float bit order == value order; ties -> min k).
// ---------------------------------------------------------------------------
__global__ __launch_bounds__(256) void vq_fallback(
        const float* __restrict__ x,
        const float* __restrict__ wT,
        const float* __restrict__ e2,
        float* __restrict__ out,
        const int* __restrict__ hard_list,
        const int* __restrict__ hard_ctr) {
    __shared__ float sx[DD];
    __shared__ unsigned long long red[256];
    const int tid = threadIdx.x;
    const int count = hard_ctr[0];

    for (int h = blockIdx.x; h < count; h += gridDim.x) {
        const int p  = hard_list[h];
        const int b  = p >> 12;
        const int hw = p & (HWW - 1);

        if (tid < DD) sx[tid] = x[(size_t)(b * DD + tid) * HWW + hw];
        __syncthreads();

        float x2 = 0.0f;
        for (int d = 0; d < DD; ++d) x2 = __fadd_rn(x2, __fmul_rn(sx[d], sx[d]));

        const int k0 = tid * 4;
        const float4* w0 = (const float4*)(wT + (size_t)(k0 + 0) * DD);
        const float4* w1 = (const float4*)(wT + (size_t)(k0 + 1) * DD);
        const float4* w2 = (const float4*)(wT + (size_t)(k0 + 2) * DD);
        const float4* w3 = (const float4*)(wT + (size_t)(k0 + 3) * DD);
        float a0 = 0.f, a1 = 0.f, a2 = 0.f, a3 = 0.f;
        for (int d4 = 0; d4 < DD / 4; ++d4) {
            float4 v0 = w0[d4], v1 = w1[d4], v2 = w2[d4], v3 = w3[d4];
            float x0 = sx[4*d4+0], x1s = sx[4*d4+1], x2s = sx[4*d4+2], x3 = sx[4*d4+3];
            a0 = __fadd_rn(a0, __fmul_rn(x0, v0.x));
            a1 = __fadd_rn(a1, __fmul_rn(x0, v1.x));
            a2 = __fadd_rn(a2, __fmul_rn(x0, v2.x));
            a3 = __fadd_rn(a3, __fmul_rn(x0, v3.x));
            a0 = __fadd_rn(a0, __fmul_rn(x1s, v0.y));
            a1 = __fadd_rn(a1, __fmul_rn(x1s, v1.y));
            a2 = __fadd_rn(a2, __fmul_rn(x1s, v2.y));
            a3 = __fadd_rn(a3, __fmul_rn(x1s, v3.y));
            a0 = __fadd_rn(a0, __fmul_rn(x2s, v0.z));
            a1 = __fadd_rn(a1, __fmul_rn(x2s, v1.z));
            a2 = __fadd_rn(a2, __fmul_rn(x2s, v2.z));
            a3 = __fadd_rn(a3, __fmul_rn(x2s, v3.z));
            a0 = __fadd_rn(a0, __fmul_rn(x3, v0.w));
            a1 = __fadd_rn(a1, __fmul_rn(x3, v1.w));
            a2 = __fadd_rn(a2, __fmul_rn(x3, v2.w));
            a3 = __fadd_rn(a3, __fmul_rn(x3, v3.w));
        }
        unsigned long long best = ~0ull;
        float d2;
        d2 = __fadd_rn(__fsub_rn(x2, 2.0f * a0), e2[k0 + 0]);
        best = min(best, ((unsigned long long)__float_as_uint(d2) << 32) | (unsigned)(k0 + 0));
        d2 = __fadd_rn(__fsub_rn(x2, 2.0f * a1), e2[k0 + 1]);
        best = min(best, ((unsigned long long)__float_as_uint(d2) << 32) | (unsigned)(k0 + 1));
        d2 = __fadd_rn(__fsub_rn(x2, 2.0f * a2), e2[k0 + 2]);
        best = min(best, ((unsigned long long)__float_as_uint(d2) << 32) | (unsigned)(k0 + 2));
        d2 = __fadd_rn(__fsub_rn(x2, 2.0f * a3), e2[k0 + 3]);
        best = min(best, ((unsigned long long)__float_as_uint(d2) << 32) | (unsigned)(k0 + 3));

        red[tid] = best;
        __syncthreads();
        for (int s = 128; s >= 1; s >>= 1) {
            if (tid < s) red[tid] = min(red[tid], red[tid + s]);
            __syncthreads();
        }
        const int bestk = (int)(red[0] & 0xffffffffu);

        if (tid == 0) out[(size_t)DD * NPIX + p] = (float)bestk;
        if (tid < DD) out[(size_t)(b * DD + tid) * HWW + hw] = wT[(size_t)bestk * DD + tid];
        __syncthreads();   // protect sx/red before next iteration
    }
}

extern "C" void kernel_launch(void* const* d_in, const int* in_sizes, int n_in,
                              void* d_out, int out_size, void* d_ws, size_t ws_size,
                              hipStream_t stream) {
    const float* x = (const float*)d_in[0];
    const float* w = (const float*)d_in[1];
    float* out = (float*)d_out;
    float* wsf = (float*)d_ws;

    float*  wT   = wsf + WS_WT;
    float*  e2   = wsf + WS_E2;
    int*    ctr  = (int*)(wsf + WS_CTR);
    int*    list = (int*)(wsf + WS_LIST);
    short8* bhi  = (short8*)(wsf + WS_BHI);
    short8* blo  = (short8*)(wsf + WS_BLO);

    prep_wt   <<<dim3(128), dim3(256), 0, stream>>>(w, wT);
    prep_bfrag<<<dim3(64),  dim3(256), 0, stream>>>(w, bhi, blo);
    prep_e2   <<<dim3(4),   dim3(256), 0, stream>>>(wT, e2, ctr);
    vq_screen <<<dim3(2048), dim3(256), 0, stream>>>(x, wT, e2, bhi, blo, out, list, ctr);
    vq_fallback<<<dim3(2048), dim3(256), 0, stream>>>(x, wT, e2, out, list, ctr);
}